// Round 14
// baseline (187.781 us; speedup 1.0000x reference)
//
#include <hip/hip_runtime.h>
#include <hip/hip_bf16.h>
#include <hip/hip_fp16.h>

// GCN 2-layer: z = relu(A(relu(A(xW1)+b1)W2)+b2), A = D^-1/2 (Adj+I) D^-1/2
// N=50000, E=800000, D=128. Output: float32.
// CSR via fixed-capacity bucket sort; GEMMs via MFMA 16x16x16 f16.
// k_fused  : edge scatter || layer-1 GEMM (blockIdx split)
// k_aggemm : agg-layer-1 -> LDS tile -> layer-2 GEMM (wave-local fusion)

#define BK 128                      // nodes per bucket
#define CAP 4096                    // edge capacity per bucket (mean 2048 + 45 sigma)
#define PACK_ROWBITS 20             // row in bits [0,20), colLocal in [20,27)
#define NB_MAX 512
#define CHUNK 2048                  // edges per scatter block (391 blocks)

typedef __attribute__((ext_vector_type(4))) _Float16 f16x4;
typedef __attribute__((ext_vector_type(4))) float f32x4;

// ---- fused: blocks [0,nScat) scatter edges; blocks [nScat,..) do layer-1 GEMM ----
__global__ __launch_bounds__(256) void k_fused(const int* __restrict__ row,
                                               const int* __restrict__ col,
                                               int* gcur, unsigned* ebuf,
                                               int E, int nb,
                                               const float* __restrict__ A,
                                               const float* __restrict__ W,
                                               __half* __restrict__ C, int M,
                                               int nScat) {
    __shared__ union {
        struct { int h[NB_MAX]; int base[NB_MAX]; } sc;
        _Float16 Wt[128][136];
    } u;
    const int t = threadIdx.x;

    if (blockIdx.x < nScat) {
        // ---------------- edge scatter ----------------
        const int e0 = blockIdx.x * CHUNK;
        int cs[CHUNK / 256];
        for (int i = t; i < nb; i += 256) u.sc.h[i] = 0;
        __syncthreads();
#pragma unroll
        for (int q = 0; q < CHUNK / 256; q++) {
            int e = e0 + q * 256 + t;
            cs[q] = (e < E) ? col[e] : -1;
            if (cs[q] >= 0) atomicAdd(&u.sc.h[cs[q] >> 7], 1);
        }
        __syncthreads();
        for (int i = t; i < nb; i += 256) {
            u.sc.base[i] = u.sc.h[i] ? atomicAdd(&gcur[i], u.sc.h[i]) : 0;
            u.sc.h[i] = 0;                          // reuse as local cursor
        }
        __syncthreads();
#pragma unroll
        for (int q = 0; q < CHUNK / 256; q++) {
            int e = e0 + q * 256 + t;
            if (cs[q] >= 0) {
                int c = cs[q];
                int b = c >> 7;
                int loc = atomicAdd(&u.sc.h[b], 1);
                ebuf[b * CAP + u.sc.base[b] + loc] =
                    (unsigned)row[e] | ((unsigned)(c & (BK - 1)) << PACK_ROWBITS);
            }
        }
    } else {
        // ---------------- layer-1 GEMM: C = f16(A @ W) ----------------
        const int bid = blockIdx.x - nScat;
        for (int idx = t; idx < 4096; idx += 256) {
            int k = idx >> 5, n4 = (idx & 31) << 2;
            float4 w4 = ((const float4*)W)[idx];    // W[k][n4..n4+3]
            u.Wt[n4 + 0][k] = (_Float16)w4.x;
            u.Wt[n4 + 1][k] = (_Float16)w4.y;
            u.Wt[n4 + 2][k] = (_Float16)w4.z;
            u.Wt[n4 + 3][k] = (_Float16)w4.w;
        }
        __syncthreads();

        const int wave = t >> 6, lane = t & 63;
        const int l16 = lane & 15, g = lane >> 4;
        const int rbase = bid * 64 + wave * 16;
        int r = rbase + l16;
        if (r >= M) r = M - 1;                      // clamp (store is guarded)

        f32x4 acc[8];
#pragma unroll
        for (int ct = 0; ct < 8; ct++) acc[ct] = (f32x4){0.f, 0.f, 0.f, 0.f};

#pragma unroll
        for (int s = 0; s < 8; s++) {
            const int k0 = s * 16 + g * 4;
            float4 a4 = *(const float4*)(A + (size_t)r * 128 + k0);
            f16x4 a = (f16x4){(_Float16)a4.x, (_Float16)a4.y,
                              (_Float16)a4.z, (_Float16)a4.w};
#pragma unroll
            for (int ct = 0; ct < 8; ct++) {
                f16x4 b = *(const f16x4*)(&u.Wt[ct * 16 + l16][k0]);
                acc[ct] = __builtin_amdgcn_mfma_f32_16x16x16f16(a, b, acc[ct], 0, 0, 0);
            }
        }

#pragma unroll
        for (int ct = 0; ct < 8; ct++) {
#pragma unroll
            for (int i = 0; i < 4; i++) {
                int rr = rbase + g * 4 + i;
                if (rr < M)
                    C[(size_t)rr * 128 + ct * 16 + l16] = __float2half(acc[ct][i]);
            }
        }
    }
}

// per-bucket: node degrees -> dinv/degi/startv (LDS scan) -> CSR fill.
// Block NB (extra) converts W2 f32 -> fp16 transposed (W2t[n][k]) for k_aggemm.
__global__ __launch_bounds__(1024) void k_bnodefill(const unsigned* __restrict__ ebuf,
                                                    const int* __restrict__ gcur,
                                                    int* degi, float* dinv, int* startv,
                                                    int* srcs, int N,
                                                    const float* __restrict__ W2,
                                                    _Float16* __restrict__ W2t, int NB) {
    const int t = threadIdx.x, b = blockIdx.x;
    if (b == NB) {                                  // W2 transpose side-job
        for (int idx = t; idx < 16384; idx += 1024) {
            int k = idx >> 7, nn = idx & 127;
            W2t[nn * 128 + k] = (_Float16)W2[k * 128 + nn];
        }
        return;
    }
    __shared__ int h[BK];      // degree, then local cursor
    __shared__ int sc[BK];     // inclusive scan
    const int s = b * CAP;
    const int cnt = gcur[b];
    if (t < BK) h[t] = 0;
    __syncthreads();
    for (int i = t; i < cnt; i += 1024)
        atomicAdd(&h[(ebuf[s + i] >> PACK_ROWBITS) & (BK - 1)], 1);
    __syncthreads();
    int deg = (t < BK) ? h[t] : 0;
    if (t < BK) sc[t] = deg;
    __syncthreads();
    for (int o = 1; o < BK; o <<= 1) {
        int x = (t < BK && t >= o) ? sc[t - o] : 0;
        __syncthreads();
        if (t < BK) sc[t] += x;
        __syncthreads();
    }
    int node = b * BK + t;
    if (t < BK) {
        int lexcl = sc[t] - deg;
        if (node < N) {
            degi[node]   = deg;
            dinv[node]   = rsqrtf((float)deg + 1.0f);   // +1 self loop
            startv[node] = s + lexcl;
        }
        h[t] = lexcl;                                   // local cursor base
    }
    __syncthreads();
    for (int i = t; i < cnt; i += 1024) {
        unsigned u = ebuf[s + i];
        int c = (u >> PACK_ROWBITS) & (BK - 1);
        int loc = atomicAdd(&h[c], 1);
        srcs[s + loc] = (int)(u & ((1u << PACK_ROWBITS) - 1));
    }
}

// --- fused agg(layer1) + GEMM(layer2): block owns 64 nodes; wave w aggregates
// nodes [w*16,w*16+16) into LDS rows = exactly its MFMA strip. B-frags from
// pre-transposed fp16 W2t in global (L2-broadcast). Hout = f16(relu-agg @ W2).
__global__ __launch_bounds__(256) void k_aggemm(const __half* __restrict__ H,
                                                const int* __restrict__ srcs,
                                                const int* __restrict__ startv,
                                                const int* __restrict__ degi,
                                                const float* __restrict__ dinv,
                                                const float* __restrict__ bias,
                                                const _Float16* __restrict__ W2t,
                                                __half* __restrict__ Hout, int n) {
    __shared__ _Float16 Zl[64][136];                // pitch 136: 2-way bank alias
    const int t = threadIdx.x;
    const int wave = t >> 6, lane = t & 63;
    const int nodeBase = blockIdx.x * 64 + wave * 16;
    const __half2* Hv = (const __half2*)H;
    const float2 b2 = ((const float2*)bias)[lane];

    for (int i = 0; i < 16; i++) {
        int node = nodeBase + i;
        int nodec = (node < n) ? node : (n - 1);    // clamp; junk rows unguarded->unused
        int s0 = startv[nodec];
        int d = degi[nodec];
        float di = dinv[nodec];
        float2 hv = __half22float2(Hv[(size_t)nodec * 64 + lane]);
        float ax = di * hv.x, ay = di * hv.y;

        for (int k = 0; k < d; k += 64) {
            int take = d - k; if (take > 64) take = 64;
            int idx = (lane < take) ? srcs[s0 + k + lane] : nodec;
            float djl = (lane < take) ? dinv[idx] : 0.f;
            for (int u = 0; u < take; u += 16) {
                int jj[16]; __half2 hh[16];
#pragma unroll
                for (int q = 0; q < 16; q++)
                    jj[q] = __shfl(idx, u + q);     // slots >= take: nodec, weight 0
#pragma unroll
                for (int q = 0; q < 16; q++)
                    hh[q] = Hv[(size_t)jj[q] * 64 + lane];
#pragma unroll
                for (int q = 0; q < 16; q++) {
                    float dj = __shfl(djl, u + q);
                    float2 v = __half22float2(hh[q]);
                    ax = fmaf(dj, v.x, ax);
                    ay = fmaf(dj, v.y, ay);
                }
            }
        }
        float ox = fmaxf(fmaf(di, ax, b2.x), 0.f);
        float oy = fmaxf(fmaf(di, ay, b2.y), 0.f);
        __half2 p = __floats2half2_rn(ox, oy);
        *(__half2*)(&Zl[wave * 16 + i][2 * lane]) = p;
    }
    __syncthreads();

    // ---- layer-2 GEMM on the wave's own 16-row strip ----
    const int l16 = lane & 15, g = lane >> 4;
    f32x4 acc[8];
#pragma unroll
    for (int ct = 0; ct < 8; ct++) acc[ct] = (f32x4){0.f, 0.f, 0.f, 0.f};

#pragma unroll
    for (int s = 0; s < 8; s++) {
        const int k0 = s * 16 + g * 4;
        f16x4 a = *(const f16x4*)(&Zl[wave * 16 + l16][k0]);
#pragma unroll
        for (int ct = 0; ct < 8; ct++) {
            f16x4 b = *(const f16x4*)(W2t + (ct * 16 + l16) * 128 + k0);
            acc[ct] = __builtin_amdgcn_mfma_f32_16x16x16f16(a, b, acc[ct], 0, 0, 0);
        }
    }

#pragma unroll
    for (int ct = 0; ct < 8; ct++) {
#pragma unroll
        for (int i = 0; i < 4; i++) {
            int rr = nodeBase + g * 4 + i;
            if (rr < n)
                Hout[(size_t)rr * 128 + ct * 16 + l16] = __float2half(acc[ct][i]);
        }
    }
}

// --- final aggregation: out = relu(di*(sum_j dj*H[j] + di*H[i]) + b), f32 out ---
__global__ __launch_bounds__(256) void k_agg(const __half* __restrict__ H,
                                             const int* __restrict__ srcs,
                                             const int* __restrict__ startv,
                                             const int* __restrict__ degi,
                                             const float* __restrict__ dinv,
                                             const float* __restrict__ bias,
                                             float* __restrict__ out, int n) {
    int wave = threadIdx.x >> 6, lane = threadIdx.x & 63;
    int node = blockIdx.x * 4 + wave;
    if (node >= n) return;
    int s0 = startv[node];
    int d = degi[node];
    float di = dinv[node];
    const __half2* Hv = (const __half2*)H;

    float2 hv = __half22float2(Hv[(size_t)node * 64 + lane]);
    float ax = di * hv.x, ay = di * hv.y;

    for (int k = 0; k < d; k += 64) {
        int take = d - k; if (take > 64) take = 64;
        int idx = (lane < take) ? srcs[s0 + k + lane] : node;
        float djl = (lane < take) ? dinv[idx] : 0.f;
        for (int u = 0; u < take; u += 16) {
            int jj[16]; __half2 hh[16];
#pragma unroll
            for (int q = 0; q < 16; q++)
                jj[q] = __shfl(idx, u + q);
#pragma unroll
            for (int q = 0; q < 16; q++)
                hh[q] = Hv[(size_t)jj[q] * 64 + lane];
#pragma unroll
            for (int q = 0; q < 16; q++) {
                float dj = __shfl(djl, u + q);
                float2 v = __half22float2(hh[q]);
                ax = fmaf(dj, v.x, ax);
                ay = fmaf(dj, v.y, ay);
            }
        }
    }
    float2 b2 = ((const float2*)bias)[lane];
    float ox = fmaxf(fmaf(di, ax, b2.x), 0.f);
    float oy = fmaxf(fmaf(di, ay, b2.y), 0.f);
    ((float2*)out)[(size_t)node * 64 + lane] = make_float2(ox, oy);
}

extern "C" void kernel_launch(void* const* d_in, const int* in_sizes, int n_in,
                              void* d_out, int out_size, void* d_ws, size_t ws_size,
                              hipStream_t stream) {
    const float* x  = (const float*)d_in[0];
    const int*   ei = (const int*)d_in[1];
    const float* W1 = (const float*)d_in[2];
    const float* b1 = (const float*)d_in[3];
    const float* W2 = (const float*)d_in[4];
    const float* b2 = (const float*)d_in[5];
    const int N = in_sizes[0] / 128;
    const int E = in_sizes[1] / 2;
    const int NB = (N + BK - 1) / BK;       // 391 buckets

    char* w = (char*)d_ws;
    auto alloc = [&](size_t bytes) -> void* {
        void* p = (void*)w;
        w += (bytes + 255) & ~(size_t)255;
        return p;
    };
    int*      degi     = (int*)alloc((size_t)N * 4);
    float*    dinv     = (float*)alloc((size_t)N * 4);
    int*      startv   = (int*)alloc((size_t)N * 4);
    int*      gcur     = (int*)alloc((size_t)NB * 4);
    unsigned* ebuf     = (unsigned*)alloc((size_t)NB * CAP * 4);
    int*      srcs     = (int*)alloc((size_t)NB * CAP * 4);
    __half*   H        = (__half*)alloc((size_t)N * 128 * 2);
    __half*   H2       = (__half*)alloc((size_t)N * 128 * 2);
    _Float16* W2t      = (_Float16*)alloc((size_t)128 * 128 * 2);

    const int* rowp = ei;
    const int* colp = ei + E;
    const int nScat = (E + CHUNK - 1) / CHUNK;       // 391
    const int nGemm = (N + 63) / 64;                 // 782

    (void)hipMemsetAsync(gcur, 0, (size_t)NB * 4, stream);
    k_fused<<<nScat + nGemm, 256, 0, stream>>>(rowp, colp, gcur, ebuf, E, NB,
                                               x, W1, H, N, nScat);
    k_bnodefill<<<NB + 1, 1024, 0, stream>>>(ebuf, gcur, degi, dinv, startv, srcs, N,
                                             W2, W2t, NB);
    k_aggemm<<<nGemm, 256, 0, stream>>>(H, srcs, startv, degi, dinv, b1, W2t, H2, N);
    k_agg<<<(N + 3) / 4, 256, 0, stream>>>(H2, srcs, startv, degi, dinv, b2,
                                           (float*)d_out, N);
}

// Round 15
// 154.182 us; speedup vs baseline: 1.2179x; 1.2179x over previous
//
#include <hip/hip_runtime.h>
#include <hip/hip_bf16.h>
#include <hip/hip_fp16.h>

// GCN 2-layer: z = relu(A(relu(A(xW1)+b1)W2)+b2), A = D^-1/2 (Adj+I) D^-1/2
// N=50000, E=800000, D=128. Output: float32.
// CSR via fixed-capacity bucket sort; GEMMs via MFMA 16x16x16 f16.
// k_fused  : edge scatter || layer-1 GEMM (blockIdx split)
// k_aggemm : 16 nodes/block: agg (4 nodes/wave) -> LDS -> cooperative 16-row GEMM

#define BK 128                      // nodes per bucket
#define CAP 4096                    // edge capacity per bucket (mean 2048 + 45 sigma)
#define PACK_ROWBITS 20             // row in bits [0,20), colLocal in [20,27)
#define NB_MAX 512
#define CHUNK 2048                  // edges per scatter block (391 blocks)

typedef __attribute__((ext_vector_type(4))) _Float16 f16x4;
typedef __attribute__((ext_vector_type(4))) float f32x4;

// ---- fused: blocks [0,nScat) scatter edges; blocks [nScat,..) do layer-1 GEMM ----
__global__ __launch_bounds__(256) void k_fused(const int* __restrict__ row,
                                               const int* __restrict__ col,
                                               int* gcur, unsigned* ebuf,
                                               int E, int nb,
                                               const float* __restrict__ A,
                                               const float* __restrict__ W,
                                               __half* __restrict__ C, int M,
                                               int nScat) {
    __shared__ union {
        struct { int h[NB_MAX]; int base[NB_MAX]; } sc;
        _Float16 Wt[128][136];
    } u;
    const int t = threadIdx.x;

    if (blockIdx.x < nScat) {
        // ---------------- edge scatter ----------------
        const int e0 = blockIdx.x * CHUNK;
        int cs[CHUNK / 256];
        for (int i = t; i < nb; i += 256) u.sc.h[i] = 0;
        __syncthreads();
#pragma unroll
        for (int q = 0; q < CHUNK / 256; q++) {
            int e = e0 + q * 256 + t;
            cs[q] = (e < E) ? col[e] : -1;
            if (cs[q] >= 0) atomicAdd(&u.sc.h[cs[q] >> 7], 1);
        }
        __syncthreads();
        for (int i = t; i < nb; i += 256) {
            u.sc.base[i] = u.sc.h[i] ? atomicAdd(&gcur[i], u.sc.h[i]) : 0;
            u.sc.h[i] = 0;                          // reuse as local cursor
        }
        __syncthreads();
#pragma unroll
        for (int q = 0; q < CHUNK / 256; q++) {
            int e = e0 + q * 256 + t;
            if (cs[q] >= 0) {
                int c = cs[q];
                int b = c >> 7;
                int loc = atomicAdd(&u.sc.h[b], 1);
                ebuf[b * CAP + u.sc.base[b] + loc] =
                    (unsigned)row[e] | ((unsigned)(c & (BK - 1)) << PACK_ROWBITS);
            }
        }
    } else {
        // ---------------- layer-1 GEMM: C = f16(A @ W) ----------------
        const int bid = blockIdx.x - nScat;
        for (int idx = t; idx < 4096; idx += 256) {
            int k = idx >> 5, n4 = (idx & 31) << 2;
            float4 w4 = ((const float4*)W)[idx];    // W[k][n4..n4+3]
            u.Wt[n4 + 0][k] = (_Float16)w4.x;
            u.Wt[n4 + 1][k] = (_Float16)w4.y;
            u.Wt[n4 + 2][k] = (_Float16)w4.z;
            u.Wt[n4 + 3][k] = (_Float16)w4.w;
        }
        __syncthreads();

        const int wave = t >> 6, lane = t & 63;
        const int l16 = lane & 15, g = lane >> 4;
        const int rbase = bid * 64 + wave * 16;
        int r = rbase + l16;
        if (r >= M) r = M - 1;                      // clamp (store is guarded)

        f32x4 acc[8];
#pragma unroll
        for (int ct = 0; ct < 8; ct++) acc[ct] = (f32x4){0.f, 0.f, 0.f, 0.f};

#pragma unroll
        for (int s = 0; s < 8; s++) {
            const int k0 = s * 16 + g * 4;
            float4 a4 = *(const float4*)(A + (size_t)r * 128 + k0);
            f16x4 a = (f16x4){(_Float16)a4.x, (_Float16)a4.y,
                              (_Float16)a4.z, (_Float16)a4.w};
#pragma unroll
            for (int ct = 0; ct < 8; ct++) {
                f16x4 b = *(const f16x4*)(&u.Wt[ct * 16 + l16][k0]);
                acc[ct] = __builtin_amdgcn_mfma_f32_16x16x16f16(a, b, acc[ct], 0, 0, 0);
            }
        }

#pragma unroll
        for (int ct = 0; ct < 8; ct++) {
#pragma unroll
            for (int i = 0; i < 4; i++) {
                int rr = rbase + g * 4 + i;
                if (rr < M)
                    C[(size_t)rr * 128 + ct * 16 + l16] = __float2half(acc[ct][i]);
            }
        }
    }
}

// per-bucket: node degrees -> dinv/degi/startv (LDS scan) -> CSR fill.
// Block NB (extra) converts W2 f32 -> fp16 transposed (W2t[n][k]) for k_aggemm.
__global__ __launch_bounds__(1024) void k_bnodefill(const unsigned* __restrict__ ebuf,
                                                    const int* __restrict__ gcur,
                                                    int* degi, float* dinv, int* startv,
                                                    int* srcs, int N,
                                                    const float* __restrict__ W2,
                                                    _Float16* __restrict__ W2t, int NB) {
    const int t = threadIdx.x, b = blockIdx.x;
    if (b == NB) {                                  // W2 transpose side-job
        for (int idx = t; idx < 16384; idx += 1024) {
            int k = idx >> 7, nn = idx & 127;
            W2t[nn * 128 + k] = (_Float16)W2[k * 128 + nn];
        }
        return;
    }
    __shared__ int h[BK];      // degree, then local cursor
    __shared__ int sc[BK];     // inclusive scan
    const int s = b * CAP;
    const int cnt = gcur[b];
    if (t < BK) h[t] = 0;
    __syncthreads();
    for (int i = t; i < cnt; i += 1024)
        atomicAdd(&h[(ebuf[s + i] >> PACK_ROWBITS) & (BK - 1)], 1);
    __syncthreads();
    int deg = (t < BK) ? h[t] : 0;
    if (t < BK) sc[t] = deg;
    __syncthreads();
    for (int o = 1; o < BK; o <<= 1) {
        int x = (t < BK && t >= o) ? sc[t - o] : 0;
        __syncthreads();
        if (t < BK) sc[t] += x;
        __syncthreads();
    }
    int node = b * BK + t;
    if (t < BK) {
        int lexcl = sc[t] - deg;
        if (node < N) {
            degi[node]   = deg;
            dinv[node]   = rsqrtf((float)deg + 1.0f);   // +1 self loop
            startv[node] = s + lexcl;
        }
        h[t] = lexcl;                                   // local cursor base
    }
    __syncthreads();
    for (int i = t; i < cnt; i += 1024) {
        unsigned u = ebuf[s + i];
        int c = (u >> PACK_ROWBITS) & (BK - 1);
        int loc = atomicAdd(&h[c], 1);
        srcs[s + loc] = (int)(u & ((1u << PACK_ROWBITS) - 1));
    }
}

// --- fused agg(layer1)+GEMM(layer2), 16 nodes/block (parallelism-preserving):
// wave w aggregates nodes base+w*4..+3 into LDS rows; after sync the 4 waves
// cooperatively compute the single 16-row MFMA strip (2 col-tiles per wave).
__global__ __launch_bounds__(256, 8) void k_aggemm(const __half* __restrict__ H,
                                                   const int* __restrict__ srcs,
                                                   const int* __restrict__ startv,
                                                   const int* __restrict__ degi,
                                                   const float* __restrict__ dinv,
                                                   const float* __restrict__ bias,
                                                   const _Float16* __restrict__ W2t,
                                                   __half* __restrict__ Hout, int n) {
    __shared__ _Float16 Zl[16][136];
    const int t = threadIdx.x;
    const int wave = t >> 6, lane = t & 63;
    const int blockBase = blockIdx.x * 16;
    const __half2* Hv = (const __half2*)H;
    const float2 b2 = ((const float2*)bias)[lane];

    for (int i = 0; i < 4; i++) {
        int node = blockBase + wave * 4 + i;
        int nodec = (node < n) ? node : (n - 1);    // clamp; junk rows row-confined
        int s0 = startv[nodec];
        int d = degi[nodec];
        float di = dinv[nodec];
        float2 hv = __half22float2(Hv[(size_t)nodec * 64 + lane]);
        float ax = di * hv.x, ay = di * hv.y;

        for (int k = 0; k < d; k += 64) {
            int take = d - k; if (take > 64) take = 64;
            int idx = (lane < take) ? srcs[s0 + k + lane] : nodec;
            float djl = (lane < take) ? dinv[idx] : 0.f;
            for (int u = 0; u < take; u += 16) {
                int jj[16]; __half2 hh[16];
#pragma unroll
                for (int q = 0; q < 16; q++)
                    jj[q] = __shfl(idx, u + q);     // slots >= take: nodec, weight 0
#pragma unroll
                for (int q = 0; q < 16; q++)
                    hh[q] = Hv[(size_t)jj[q] * 64 + lane];
#pragma unroll
                for (int q = 0; q < 16; q++) {
                    float dj = __shfl(djl, u + q);
                    float2 v = __half22float2(hh[q]);
                    ax = fmaf(dj, v.x, ax);
                    ay = fmaf(dj, v.y, ay);
                }
            }
        }
        float ox = fmaxf(fmaf(di, ax, b2.x), 0.f);
        float oy = fmaxf(fmaf(di, ay, b2.y), 0.f);
        *(__half2*)(&Zl[wave * 4 + i][2 * lane]) = __floats2half2_rn(ox, oy);
    }
    __syncthreads();

    // ---- cooperative 16-row layer-2 GEMM: wave handles col-tiles 2w, 2w+1 ----
    const int l16 = lane & 15, g = lane >> 4;
    f32x4 acc[2];
    acc[0] = (f32x4){0.f, 0.f, 0.f, 0.f};
    acc[1] = (f32x4){0.f, 0.f, 0.f, 0.f};

#pragma unroll
    for (int s = 0; s < 8; s++) {
        const int k0 = s * 16 + g * 4;
        f16x4 a = *(const f16x4*)(&Zl[l16][k0]);
#pragma unroll
        for (int cc = 0; cc < 2; cc++) {
            int ct = wave * 2 + cc;
            f16x4 b = *(const f16x4*)(W2t + (size_t)(ct * 16 + l16) * 128 + k0);
            acc[cc] = __builtin_amdgcn_mfma_f32_16x16x16f16(a, b, acc[cc], 0, 0, 0);
        }
    }

#pragma unroll
    for (int cc = 0; cc < 2; cc++) {
        int ct = wave * 2 + cc;
#pragma unroll
        for (int i = 0; i < 4; i++) {
            int rr = blockBase + g * 4 + i;
            if (rr < n)
                Hout[(size_t)rr * 128 + ct * 16 + l16] = __float2half(acc[cc][i]);
        }
    }
}

// --- final aggregation: out = relu(di*(sum_j dj*H[j] + di*H[i]) + b), f32 out ---
__global__ __launch_bounds__(256) void k_agg(const __half* __restrict__ H,
                                             const int* __restrict__ srcs,
                                             const int* __restrict__ startv,
                                             const int* __restrict__ degi,
                                             const float* __restrict__ dinv,
                                             const float* __restrict__ bias,
                                             float* __restrict__ out, int n) {
    int wave = threadIdx.x >> 6, lane = threadIdx.x & 63;
    int node = blockIdx.x * 4 + wave;
    if (node >= n) return;
    int s0 = startv[node];
    int d = degi[node];
    float di = dinv[node];
    const __half2* Hv = (const __half2*)H;

    float2 hv = __half22float2(Hv[(size_t)node * 64 + lane]);
    float ax = di * hv.x, ay = di * hv.y;

    for (int k = 0; k < d; k += 64) {
        int take = d - k; if (take > 64) take = 64;
        int idx = (lane < take) ? srcs[s0 + k + lane] : node;
        float djl = (lane < take) ? dinv[idx] : 0.f;
        for (int u = 0; u < take; u += 16) {
            int jj[16]; __half2 hh[16];
#pragma unroll
            for (int q = 0; q < 16; q++)
                jj[q] = __shfl(idx, u + q);
#pragma unroll
            for (int q = 0; q < 16; q++)
                hh[q] = Hv[(size_t)jj[q] * 64 + lane];
#pragma unroll
            for (int q = 0; q < 16; q++) {
                float dj = __shfl(djl, u + q);
                float2 v = __half22float2(hh[q]);
                ax = fmaf(dj, v.x, ax);
                ay = fmaf(dj, v.y, ay);
            }
        }
    }
    float2 b2 = ((const float2*)bias)[lane];
    float ox = fmaxf(fmaf(di, ax, b2.x), 0.f);
    float oy = fmaxf(fmaf(di, ay, b2.y), 0.f);
    ((float2*)out)[(size_t)node * 64 + lane] = make_float2(ox, oy);
}

extern "C" void kernel_launch(void* const* d_in, const int* in_sizes, int n_in,
                              void* d_out, int out_size, void* d_ws, size_t ws_size,
                              hipStream_t stream) {
    const float* x  = (const float*)d_in[0];
    const int*   ei = (const int*)d_in[1];
    const float* W1 = (const float*)d_in[2];
    const float* b1 = (const float*)d_in[3];
    const float* W2 = (const float*)d_in[4];
    const float* b2 = (const float*)d_in[5];
    const int N = in_sizes[0] / 128;
    const int E = in_sizes[1] / 2;
    const int NB = (N + BK - 1) / BK;       // 391 buckets

    char* w = (char*)d_ws;
    auto alloc = [&](size_t bytes) -> void* {
        void* p = (void*)w;
        w += (bytes + 255) & ~(size_t)255;
        return p;
    };
    int*      degi     = (int*)alloc((size_t)N * 4);
    float*    dinv     = (float*)alloc((size_t)N * 4);
    int*      startv   = (int*)alloc((size_t)N * 4);
    int*      gcur     = (int*)alloc((size_t)NB * 4);
    unsigned* ebuf     = (unsigned*)alloc((size_t)NB * CAP * 4);
    int*      srcs     = (int*)alloc((size_t)NB * CAP * 4);
    __half*   H        = (__half*)alloc((size_t)N * 128 * 2);
    __half*   H2       = (__half*)alloc((size_t)N * 128 * 2);
    _Float16* W2t      = (_Float16*)alloc((size_t)128 * 128 * 2);

    const int* rowp = ei;
    const int* colp = ei + E;
    const int nScat = (E + CHUNK - 1) / CHUNK;       // 391
    const int nGemm = (N + 63) / 64;                 // 782

    (void)hipMemsetAsync(gcur, 0, (size_t)NB * 4, stream);
    k_fused<<<nScat + nGemm, 256, 0, stream>>>(rowp, colp, gcur, ebuf, E, NB,
                                               x, W1, H, N, nScat);
    k_bnodefill<<<NB + 1, 1024, 0, stream>>>(ebuf, gcur, degi, dinv, startv, srcs, N,
                                             W2, W2t, NB);
    k_aggemm<<<(N + 15) / 16, 256, 0, stream>>>(H, srcs, startv, degi, dinv, b1,
                                                W2t, H2, N);
    k_agg<<<(N + 3) / 4, 256, 0, stream>>>(H2, srcs, startv, degi, dinv, b2,
                                           (float*)d_out, N);
}

// Round 17
// 144.797 us; speedup vs baseline: 1.2969x; 1.0648x over previous
//
#include <hip/hip_runtime.h>
#include <hip/hip_bf16.h>
#include <hip/hip_fp16.h>

// GCN 2-layer: z = relu(A(relu(A(xW1)+b1)W2)+b2), A = D^-1/2 (Adj+I) D^-1/2
// N=50000, E=800000, D=128. Output: float32.
// CSR via fixed-capacity bucket sort; GEMM via MFMA 16x16x16 f16.
// Layer-1 GEMM fused with the edge scatter (independent stages, one dispatch).
// [Round-13 structure = best measured 144.28 us. Fusion of agg+gemm2 tested
//  twice (64- and 16-node variants): loses TLP/ILP. Aggregation is at the
//  fp16 byte-service floor; fp8 fails the error budget.]

#define BK 128                      // nodes per bucket
#define CAP 4096                    // edge capacity per bucket (mean 2048 + 45 sigma)
#define PACK_ROWBITS 20             // row in bits [0,20), colLocal in [20,27)
#define NB_MAX 512
#define CHUNK 2048                  // edges per scatter block (391 blocks)

typedef __attribute__((ext_vector_type(4))) _Float16 f16x4;
typedef __attribute__((ext_vector_type(4))) float f32x4;

// ---- fused: blocks [0,nScat) scatter edges; blocks [nScat,..) do layer-1 GEMM ----
__global__ __launch_bounds__(256) void k_fused(const int* __restrict__ row,
                                               const int* __restrict__ col,
                                               int* gcur, unsigned* ebuf,
                                               int E, int nb,
                                               const float* __restrict__ A,
                                               const float* __restrict__ W,
                                               __half* __restrict__ C, int M,
                                               int nScat) {
    __shared__ union {
        struct { int h[NB_MAX]; int base[NB_MAX]; } sc;
        _Float16 Wt[128][136];
    } u;
    const int t = threadIdx.x;

    if (blockIdx.x < nScat) {
        // ---------------- edge scatter ----------------
        const int e0 = blockIdx.x * CHUNK;
        int cs[CHUNK / 256];
        for (int i = t; i < nb; i += 256) u.sc.h[i] = 0;
        __syncthreads();
#pragma unroll
        for (int q = 0; q < CHUNK / 256; q++) {
            int e = e0 + q * 256 + t;
            cs[q] = (e < E) ? col[e] : -1;
            if (cs[q] >= 0) atomicAdd(&u.sc.h[cs[q] >> 7], 1);
        }
        __syncthreads();
        for (int i = t; i < nb; i += 256) {
            u.sc.base[i] = u.sc.h[i] ? atomicAdd(&gcur[i], u.sc.h[i]) : 0;
            u.sc.h[i] = 0;                          // reuse as local cursor
        }
        __syncthreads();
#pragma unroll
        for (int q = 0; q < CHUNK / 256; q++) {
            int e = e0 + q * 256 + t;
            if (cs[q] >= 0) {
                int c = cs[q];
                int b = c >> 7;
                int loc = atomicAdd(&u.sc.h[b], 1);
                ebuf[b * CAP + u.sc.base[b] + loc] =
                    (unsigned)row[e] | ((unsigned)(c & (BK - 1)) << PACK_ROWBITS);
            }
        }
    } else {
        // ---------------- layer-1 GEMM: C = f16(A @ W) ----------------
        const int bid = blockIdx.x - nScat;
        for (int idx = t; idx < 4096; idx += 256) {
            int k = idx >> 5, n4 = (idx & 31) << 2;
            float4 w4 = ((const float4*)W)[idx];    // W[k][n4..n4+3]
            u.Wt[n4 + 0][k] = (_Float16)w4.x;
            u.Wt[n4 + 1][k] = (_Float16)w4.y;
            u.Wt[n4 + 2][k] = (_Float16)w4.z;
            u.Wt[n4 + 3][k] = (_Float16)w4.w;
        }
        __syncthreads();

        const int wave = t >> 6, lane = t & 63;
        const int l16 = lane & 15, g = lane >> 4;
        const int rbase = bid * 64 + wave * 16;
        int r = rbase + l16;
        if (r >= M) r = M - 1;                      // clamp (store is guarded)

        f32x4 acc[8];
#pragma unroll
        for (int ct = 0; ct < 8; ct++) acc[ct] = (f32x4){0.f, 0.f, 0.f, 0.f};

#pragma unroll
        for (int s = 0; s < 8; s++) {
            const int k0 = s * 16 + g * 4;
            float4 a4 = *(const float4*)(A + (size_t)r * 128 + k0);
            f16x4 a = (f16x4){(_Float16)a4.x, (_Float16)a4.y,
                              (_Float16)a4.z, (_Float16)a4.w};
#pragma unroll
            for (int ct = 0; ct < 8; ct++) {
                f16x4 b = *(const f16x4*)(&u.Wt[ct * 16 + l16][k0]);
                acc[ct] = __builtin_amdgcn_mfma_f32_16x16x16f16(a, b, acc[ct], 0, 0, 0);
            }
        }

#pragma unroll
        for (int ct = 0; ct < 8; ct++) {
#pragma unroll
            for (int i = 0; i < 4; i++) {
                int rr = rbase + g * 4 + i;
                if (rr < M)
                    C[(size_t)rr * 128 + ct * 16 + l16] = __float2half(acc[ct][i]);
            }
        }
    }
}

// per-bucket: node degrees -> dinv/degi/startv (LDS scan) -> CSR fill.
// 1024 threads (16 waves): the 2 ebuf passes are latency-bound at 391 blocks.
__global__ __launch_bounds__(1024) void k_bnodefill(const unsigned* __restrict__ ebuf,
                                                    const int* __restrict__ gcur,
                                                    int* degi, float* dinv, int* startv,
                                                    int* srcs, int N) {
    __shared__ int h[BK];      // degree, then local cursor
    __shared__ int sc[BK];     // inclusive scan
    const int t = threadIdx.x, b = blockIdx.x;
    const int s = b * CAP;
    const int cnt = gcur[b];
    if (t < BK) h[t] = 0;
    __syncthreads();
    for (int i = t; i < cnt; i += 1024)
        atomicAdd(&h[(ebuf[s + i] >> PACK_ROWBITS) & (BK - 1)], 1);
    __syncthreads();
    int deg = (t < BK) ? h[t] : 0;
    if (t < BK) sc[t] = deg;
    __syncthreads();
    for (int o = 1; o < BK; o <<= 1) {
        int x = (t < BK && t >= o) ? sc[t - o] : 0;
        __syncthreads();
        if (t < BK) sc[t] += x;
        __syncthreads();
    }
    int node = b * BK + t;
    if (t < BK) {
        int lexcl = sc[t] - deg;
        if (node < N) {
            degi[node]   = deg;
            dinv[node]   = rsqrtf((float)deg + 1.0f);   // +1 self loop
            startv[node] = s + lexcl;
        }
        h[t] = lexcl;                                   // local cursor base
    }
    __syncthreads();
    for (int i = t; i < cnt; i += 1024) {
        unsigned u = ebuf[s + i];
        int c = (u >> PACK_ROWBITS) & (BK - 1);
        int loc = atomicAdd(&h[c], 1);
        srcs[s + loc] = (int)(u & ((1u << PACK_ROWBITS) - 1));
    }
}

// --- layer-2 GEMM: C[M,128] = f16(A_f16[M,128] @ W[128,128]) ---
__global__ __launch_bounds__(256) void k_gemm2(const __half* __restrict__ A,
                                               const float* __restrict__ W,
                                               __half* __restrict__ C, int M) {
    __shared__ _Float16 Wt[128][136];
    const int t = threadIdx.x;
    for (int idx = t; idx < 4096; idx += 256) {
        int k = idx >> 5, n4 = (idx & 31) << 2;
        float4 w4 = ((const float4*)W)[idx];
        Wt[n4 + 0][k] = (_Float16)w4.x;
        Wt[n4 + 1][k] = (_Float16)w4.y;
        Wt[n4 + 2][k] = (_Float16)w4.z;
        Wt[n4 + 3][k] = (_Float16)w4.w;
    }
    __syncthreads();

    const int wave = t >> 6, lane = t & 63;
    const int l16 = lane & 15, g = lane >> 4;
    const int rbase = blockIdx.x * 64 + wave * 16;
    int r = rbase + l16;
    if (r >= M) r = M - 1;

    f32x4 acc[8];
#pragma unroll
    for (int ct = 0; ct < 8; ct++) acc[ct] = (f32x4){0.f, 0.f, 0.f, 0.f};

#pragma unroll
    for (int s = 0; s < 8; s++) {
        const int k0 = s * 16 + g * 4;
        f16x4 a = *(const f16x4*)((const _Float16*)A + (size_t)r * 128 + k0);
#pragma unroll
        for (int ct = 0; ct < 8; ct++) {
            f16x4 b = *(const f16x4*)(&Wt[ct * 16 + l16][k0]);
            acc[ct] = __builtin_amdgcn_mfma_f32_16x16x16f16(a, b, acc[ct], 0, 0, 0);
        }
    }

#pragma unroll
    for (int ct = 0; ct < 8; ct++) {
#pragma unroll
        for (int i = 0; i < 4; i++) {
            int rr = rbase + g * 4 + i;
            if (rr < M)
                C[(size_t)rr * 128 + ct * 16 + l16] = __float2half(acc[ct][i]);
        }
    }
}

// --- aggregation: out = relu(di*(sum_j dj*H[j] + di*H[i]) + b), H fp16 ---
// one wave per node; padded 16-deep rounds; rows staged as raw __half2.
__global__ __launch_bounds__(256) void k_agg(const __half* __restrict__ H,
                                             const int* __restrict__ srcs,
                                             const int* __restrict__ startv,
                                             const int* __restrict__ degi,
                                             const float* __restrict__ dinv,
                                             const float* __restrict__ bias,
                                             float* __restrict__ outF,
                                             __half* __restrict__ outH, int n) {
    int wave = threadIdx.x >> 6, lane = threadIdx.x & 63;
    int node = blockIdx.x * 4 + wave;
    if (node >= n) return;
    int s0 = startv[node];
    int d = degi[node];
    float di = dinv[node];
    const __half2* Hv = (const __half2*)H;

    float2 hv = __half22float2(Hv[(size_t)node * 64 + lane]);
    float ax = di * hv.x, ay = di * hv.y;

    for (int k = 0; k < d; k += 64) {
        int take = d - k; if (take > 64) take = 64;
        int idx = (lane < take) ? srcs[s0 + k + lane] : node;
        float djl = (lane < take) ? dinv[idx] : 0.f;
        for (int u = 0; u < take; u += 16) {
            int jj[16]; __half2 hh[16];
#pragma unroll
            for (int q = 0; q < 16; q++)
                jj[q] = __shfl(idx, u + q);      // slots >= take: node, weight 0
#pragma unroll
            for (int q = 0; q < 16; q++)
                hh[q] = Hv[(size_t)jj[q] * 64 + lane];
#pragma unroll
            for (int q = 0; q < 16; q++) {
                float dj = __shfl(djl, u + q);
                float2 v = __half22float2(hh[q]);
                ax = fmaf(dj, v.x, ax);
                ay = fmaf(dj, v.y, ay);
            }
        }
    }
    float2 b2 = ((const float2*)bias)[lane];
    float ox = fmaxf(fmaf(di, ax, b2.x), 0.f);
    float oy = fmaxf(fmaf(di, ay, b2.y), 0.f);
    if (outF) {
        ((float2*)outF)[(size_t)node * 64 + lane] = make_float2(ox, oy);
    } else {
        __half2 p = __floats2half2_rn(ox, oy);
        ((__half2*)outH)[(size_t)node * 64 + lane] = p;
    }
}

extern "C" void kernel_launch(void* const* d_in, const int* in_sizes, int n_in,
                              void* d_out, int out_size, void* d_ws, size_t ws_size,
                              hipStream_t stream) {
    const float* x  = (const float*)d_in[0];
    const int*   ei = (const int*)d_in[1];
    const float* W1 = (const float*)d_in[2];
    const float* b1 = (const float*)d_in[3];
    const float* W2 = (const float*)d_in[4];
    const float* b2 = (const float*)d_in[5];
    const int N = in_sizes[0] / 128;
    const int E = in_sizes[1] / 2;
    const int NB = (N + BK - 1) / BK;       // 391 buckets

    char* w = (char*)d_ws;
    auto alloc = [&](size_t bytes) -> void* {
        void* p = (void*)w;
        w += (bytes + 255) & ~(size_t)255;
        return p;
    };
    int*      degi     = (int*)alloc((size_t)N * 4);
    float*    dinv     = (float*)alloc((size_t)N * 4);
    int*      startv   = (int*)alloc((size_t)N * 4);
    int*      gcur     = (int*)alloc((size_t)NB * 4);
    unsigned* ebuf     = (unsigned*)alloc((size_t)NB * CAP * 4);
    int*      srcs     = (int*)alloc((size_t)NB * CAP * 4);
    __half*   H        = (__half*)alloc((size_t)N * 128 * 2);
    __half*   Z        = (__half*)alloc((size_t)N * 128 * 2);

    const int* rowp = ei;
    const int* colp = ei + E;
    const int nScat = (E + CHUNK - 1) / CHUNK;       // 391
    const int nGemm = (N + 63) / 64;                 // 782

    (void)hipMemsetAsync(gcur, 0, (size_t)NB * 4, stream);
    k_fused<<<nScat + nGemm, 256, 0, stream>>>(rowp, colp, gcur, ebuf, E, NB,
                                               x, W1, H, N, nScat);
    k_bnodefill<<<NB, 1024, 0, stream>>>(ebuf, gcur, degi, dinv, startv, srcs, N);

    k_agg<<<(N + 3) / 4, 256, 0, stream>>>(H, srcs, startv, degi, dinv, b1,
                                           nullptr, Z, N);
    k_gemm2<<<nGemm, 256, 0, stream>>>(Z, W2, H, N);
    k_agg<<<(N + 3) / 4, 256, 0, stream>>>(H, srcs, startv, degi, dinv, b2,
                                           (float*)d_out, nullptr, N);
}